// Round 7
// baseline (210.241 us; speedup 1.0000x reference)
//
#include <hip/hip_runtime.h>
#include <hip/hip_fp16.h>
#include <cstdint>

#define SEQ 4096
#define DIM 1024

typedef _Float16 f16x8 __attribute__((ext_vector_type(8)));
typedef float f32x16 __attribute__((ext_vector_type(16)));
typedef __attribute__((address_space(1))) void as1_void;
typedef __attribute__((address_space(3))) void as3_void;

__device__ __forceinline__ ushort f2h(float f) {
  _Float16 h = (_Float16)f;
  return __builtin_bit_cast(ushort, h);
}

// ---------------- fused conversions: z<3 -> W transpose+cvt, z==3 -> X cvt ----------------
__global__ void convert_all_kernel(const float* __restrict__ X, const float* __restrict__ Wk,
                                   const float* __restrict__ Wv, const float* __restrict__ Wq,
                                   ushort* __restrict__ Xh, ushort* __restrict__ Wt) {
  const int z = blockIdx.z;
  const int tx = threadIdx.x, ty = threadIdx.y;  // (32,8)
  if (z == 3) {
    const int bid = blockIdx.y * 32 + blockIdx.x;
    const int t = ty * 32 + tx;
#pragma unroll
    for (int k = 0; k < 4; k++) {
      int i = bid * 1024 + k * 256 + t;
      float4 v = reinterpret_cast<const float4*>(X)[i];
      ushort4 o = { f2h(v.x), f2h(v.y), f2h(v.z), f2h(v.w) };
      reinterpret_cast<ushort4*>(Xh)[i] = o;
    }
    return;
  }
  __shared__ float tile[32][33];
  const float* W = (z == 0) ? Wk : (z == 1) ? Wv : Wq;
  int n0 = blockIdx.x * 32, k0 = blockIdx.y * 32;
#pragma unroll
  for (int r = 0; r < 4; r++) {
    int k = ty + r * 8;
    tile[k][tx] = W[(size_t)(k0 + k) * DIM + n0 + tx];
  }
  __syncthreads();
  ushort* out = Wt + (size_t)z * DIM * DIM;
#pragma unroll
  for (int r = 0; r < 4; r++) {
    int n = ty + r * 8;
    out[(size_t)(n0 + n) * DIM + k0 + tx] = f2h(tile[tx][n]);
  }
}

// ---------------- core GEMM: 512 threads, 256x256 tile, double-buffered LDS ----------------
// 8 waves (4m x 2n) of 64x128; BK=64; 32x32x16 f16 MFMA; acc 128 VGPR/wave.
// Double-buffer: loads(k+1) issued right after the barrier that drained loads(k),
// so they fly during compute(k) — the vmcnt(0) barrier drain no longer serializes
// staging with compute (the m97-structure's ~60% stall).
// XOR chunk swizzle key(r) = (r&7)^((r>>3)&3): invariant under +32/+64 offsets;
// verified 0 bank conflicts (R4-R6).
__device__ __forceinline__ void gemm512(const ushort* __restrict__ A,
                                        const ushort* __restrict__ B,
                                        ushort* __restrict__ C,
                                        int N, int K, int m0, int n0,
                                        int kt0, int ktend) {
  constexpr int BK = 64;
  __shared__ __align__(16) ushort As[2][256 * BK];  // 2 x 32 KB
  __shared__ __align__(16) ushort Bs[2][256 * BK];  // 2 x 32 KB
  const int tid = threadIdx.x;
  const int wave = tid >> 6, lane = tid & 63;
  const int l31 = lane & 31, khalf = lane >> 5;
  const int wm = (wave & 3) * 64, wn = (wave >> 2) * 128;

  const int srow = tid >> 3;                         // [0,64)
  const int skey = (srow & 7) ^ ((srow >> 3) & 3);
  const int sce = (((tid & 7) ^ skey) * 8);          // swizzled source chunk (elems)
  const int rk = (l31 & 7) ^ ((l31 >> 3) & 3);       // read-side key

  const ushort* Abase = A + (size_t)(m0 + srow) * K + sce;
  const ushort* Bbase = B + (size_t)(n0 + srow) * K + sce;

  f32x16 acc[2][4];
#pragma unroll
  for (int i = 0; i < 2; i++)
#pragma unroll
    for (int j = 0; j < 4; j++)
#pragma unroll
      for (int r = 0; r < 16; r++) acc[i][j][r] = 0.f;

  const int niter = (ktend - kt0) / BK;

  // prefetch iter 0 into buffer 0
#pragma unroll
  for (int q = 0; q < 4; q++) {
    __builtin_amdgcn_global_load_lds((const as1_void*)(Abase + (size_t)q * 64 * K + kt0),
                                     (as3_void*)&As[0][wave * 512 + q * 4096], 16, 0, 0);
    __builtin_amdgcn_global_load_lds((const as1_void*)(Bbase + (size_t)q * 64 * K + kt0),
                                     (as3_void*)&Bs[0][wave * 512 + q * 4096], 16, 0, 0);
  }

  for (int it = 0; it < niter; ++it) {
    __syncthreads();  // drains loads(it) [issued one iter ago]; LDS reuse safe
    if (it + 1 < niter) {
      const int kt = kt0 + (it + 1) * BK;
      const int nb = (it + 1) & 1;
#pragma unroll
      for (int q = 0; q < 4; q++) {
        __builtin_amdgcn_global_load_lds((const as1_void*)(Abase + (size_t)q * 64 * K + kt),
                                         (as3_void*)&As[nb][wave * 512 + q * 4096], 16, 0, 0);
        __builtin_amdgcn_global_load_lds((const as1_void*)(Bbase + (size_t)q * 64 * K + kt),
                                         (as3_void*)&Bs[nb][wave * 512 + q * 4096], 16, 0, 0);
      }
    }
    const int cb = it & 1;
#pragma unroll
    for (int ks = 0; ks < 4; ks++) {
      f16x8 af[2], bfr[4];
      const int ck = (ks * 2 + khalf);
#pragma unroll
      for (int i = 0; i < 2; i++)
        af[i] = *reinterpret_cast<const f16x8*>(
            &As[cb][(wm + i * 32 + l31) * BK + ((ck ^ rk) * 8)]);
#pragma unroll
      for (int j = 0; j < 4; j++)
        bfr[j] = *reinterpret_cast<const f16x8*>(
            &Bs[cb][(wn + j * 32 + l31) * BK + ((ck ^ rk) * 8)]);
#pragma unroll
      for (int i = 0; i < 2; i++)
#pragma unroll
        for (int j = 0; j < 4; j++)
          acc[i][j] = __builtin_amdgcn_mfma_f32_32x32x16_f16(af[i], bfr[j], acc[i][j], 0, 0, 0);
    }
  }

  // epilogue: 32x32 C/D layout col=lane&31, row=(reg&3)+8*(reg>>2)+4*(lane>>5)  [m74/m101]
#pragma unroll
  for (int i = 0; i < 2; i++)
#pragma unroll
    for (int j = 0; j < 4; j++)
#pragma unroll
      for (int r = 0; r < 16; r++) {
        int row = m0 + wm + i * 32 + (r & 3) + 8 * (r >> 2) + 4 * khalf;
        int col = n0 + wn + j * 32 + l31;
        C[(size_t)row * N + col] = f2h(acc[i][j][r]);
      }
}

// ---------------- fused K/Q/V^T projections (192 blocks) ----------------
__global__ __launch_bounds__(512, 2) void proj_kernel(const ushort* __restrict__ Xh,
                                                      const ushort* __restrict__ Wt,
                                                      ushort* __restrict__ Kh,
                                                      ushort* __restrict__ Qh,
                                                      ushort* __restrict__ Vt) {
  const int z = blockIdx.z;
  const int bx = blockIdx.x;  // [0,64)
  if (z < 2) {
    // K/Q: [SEQ,DIM], tiles 16x4
    const ushort* B = Wt + (size_t)(z == 0 ? 0 : 2) * DIM * DIM;
    ushort* C = (z == 0) ? Kh : Qh;
    gemm512(Xh, B, C, DIM, DIM, (bx >> 2) * 256, (bx & 3) * 256, 0, DIM);
  } else {
    // V^T: [DIM,SEQ], tiles 4x16
    gemm512(Wt + (size_t)DIM * DIM, Xh, Vt, SEQ, DIM,
            (bx >> 4) * 256, (bx & 15) * 256, 0, DIM);
  }
}

// ---------------- S = K @ Q^T (fp16), 256x256 tiles, XCD-chunked ----------------
__global__ __launch_bounds__(512, 2) void score_kernel(const ushort* __restrict__ Kh,
                                                       const ushort* __restrict__ Qh,
                                                       ushort* __restrict__ S) {
  const int f = blockIdx.x;           // [0,256)
  const int xcd = f & 7;
  const int r = f >> 3;               // [0,32)
  const int g = xcd * 2 + (r >> 4);   // 4x4 supertile index [0,16)
  const int w = r & 15;
  const int sx = w & 3, sy = w >> 2;
  const int tx = (g & 3) * 4 + sx;    // [0,16)
  const int ty = (g >> 2) * 4 + sy;   // [0,16)
  gemm512(Kh, Qh, S, SEQ, DIM, ty * 256, tx * 256, 0, DIM);
}

// ---------------- O partials: split-K=4, 256x256 tiles, fp16 ----------------
__global__ __launch_bounds__(512, 2) void out_splitk_kernel(const ushort* __restrict__ P,
                                                            const ushort* __restrict__ Vt,
                                                            ushort* __restrict__ Part) {
  const int f = blockIdx.x;           // [0,256)
  const int xcd = f & 7;
  const int r = f >> 3;               // [0,32)
  const int z = r >> 3;               // split slice [0,4)
  const int u = r & 7;
  const int t = xcd * 8 + u;          // [0,64)
  const int ty = t >> 2, tx = t & 3;  // 16 x 4 tiles
  ushort* C = Part + (size_t)z * SEQ * DIM;
  gemm512(P, Vt, C, DIM, SEQ, ty * 256, tx * 256,
          z * (SEQ / 4), (z + 1) * (SEQ / 4));
}

__global__ void reduce4_kernel(const ushort* __restrict__ Part, float* __restrict__ out, int n8) {
  int i = blockIdx.x * blockDim.x + threadIdx.x;
  if (i >= n8) return;
  const f16x8* p0 = reinterpret_cast<const f16x8*>(Part);
  const f16x8* p1 = p0 + n8;
  const f16x8* p2 = p1 + n8;
  const f16x8* p3 = p2 + n8;
  f16x8 a = p0[i], b = p1[i], c = p2[i], d = p3[i];
  float4 lo, hi;
  lo.x = (float)a[0] + (float)b[0] + (float)c[0] + (float)d[0];
  lo.y = (float)a[1] + (float)b[1] + (float)c[1] + (float)d[1];
  lo.z = (float)a[2] + (float)b[2] + (float)c[2] + (float)d[2];
  lo.w = (float)a[3] + (float)b[3] + (float)c[3] + (float)d[3];
  hi.x = (float)a[4] + (float)b[4] + (float)c[4] + (float)d[4];
  hi.y = (float)a[5] + (float)b[5] + (float)c[5] + (float)d[5];
  hi.z = (float)a[6] + (float)b[6] + (float)c[6] + (float)d[6];
  hi.w = (float)a[7] + (float)b[7] + (float)c[7] + (float)d[7];
  reinterpret_cast<float4*>(out)[i * 2] = lo;
  reinterpret_cast<float4*>(out)[i * 2 + 1] = hi;
}

// ---------------- row softmax: one wave per row ----------------
__global__ __launch_bounds__(256) void softmax_kernel(const ushort* __restrict__ S,
                                                      ushort* __restrict__ P) {
  const int wave = threadIdx.x >> 6, lane = threadIdx.x & 63;
  const int row = blockIdx.x * 4 + wave;
  const ushort* s = S + (size_t)row * SEQ;
  float v[64];
#pragma unroll
  for (int i = 0; i < 8; i++) {
    f16x8 h = reinterpret_cast<const f16x8*>(s)[i * 64 + lane];
#pragma unroll
    for (int j = 0; j < 8; j++) v[i * 8 + j] = (float)h[j];
  }
  float m = v[0];
#pragma unroll
  for (int j = 1; j < 64; j++) m = fmaxf(m, v[j]);
#pragma unroll
  for (int o = 32; o > 0; o >>= 1) m = fmaxf(m, __shfl_xor(m, o, 64));
  float sum = 0.f;
#pragma unroll
  for (int j = 0; j < 64; j++) {
    v[j] = __expf(v[j] - m);
    sum += v[j];
  }
#pragma unroll
  for (int o = 32; o > 0; o >>= 1) sum += __shfl_xor(sum, o, 64);
  float inv = 1.0f / sum;
  ushort* p = P + (size_t)row * SEQ;
#pragma unroll
  for (int i = 0; i < 8; i++) {
    f16x8 h;
#pragma unroll
    for (int j = 0; j < 8; j++) h[j] = (_Float16)(v[i * 8 + j] * inv);
    reinterpret_cast<f16x8*>(p)[i * 64 + lane] = h;
  }
}

extern "C" void kernel_launch(void* const* d_in, const int* in_sizes, int n_in,
                              void* d_out, int out_size, void* d_ws, size_t ws_size,
                              hipStream_t stream) {
  const float* X = (const float*)d_in[0];
  const float* Wk = (const float*)d_in[1];
  const float* Wv = (const float*)d_in[2];
  const float* Wq = (const float*)d_in[3];

  char* ws = (char*)d_ws;
  size_t off = 0;
  ushort* Xh = (ushort*)(ws + off); off += (size_t)SEQ * DIM * 2;      // 8 MB
  ushort* Wt = (ushort*)(ws + off); off += (size_t)3 * DIM * DIM * 2;  // 6 MB
  ushort* Kh = (ushort*)(ws + off); off += (size_t)SEQ * DIM * 2;      // 8 MB
  ushort* Qh = (ushort*)(ws + off); off += (size_t)SEQ * DIM * 2;      // 8 MB
  ushort* Vt = (ushort*)(ws + off); off += (size_t)SEQ * DIM * 2;      // 8 MB
  ushort* S = (ushort*)(ws + off);  off += (size_t)SEQ * SEQ * 2;      // 32 MB (reused as partials)
  ushort* P = (ushort*)(ws + off);  off += (size_t)SEQ * SEQ * 2;      // 32 MB

  ushort* Part = S;  // 4 x [SEQ,DIM] fp16 partials alias S; S dead after softmax

  convert_all_kernel<<<dim3(32, 32, 4), dim3(32, 8), 0, stream>>>(X, Wk, Wv, Wq, Xh, Wt);
  proj_kernel<<<dim3(64, 1, 3), 512, 0, stream>>>(Xh, Wt, Kh, Qh, Vt);
  score_kernel<<<256, 512, 0, stream>>>(Kh, Qh, S);
  softmax_kernel<<<1024, 256, 0, stream>>>(S, P);
  out_splitk_kernel<<<256, 512, 0, stream>>>(P, Vt, Part);
  reduce4_kernel<<<SEQ * DIM / 8 / 256, 256, 0, stream>>>(Part, (float*)d_out, SEQ * DIM / 8);
}